// Round 1
// baseline (456.500 us; speedup 1.0000x reference)
//
#include <hip/hip_runtime.h>
#include <hip/hip_bf16.h>
#include <float.h>

typedef _Float16 f16;
typedef __attribute__((ext_vector_type(8))) _Float16 half8;
typedef __attribute__((ext_vector_type(4))) float floatx4;

// Problem constants
#define DIM   128
#define HW    4096
#define NPOS  131072
#define K     512
#define ZSTRIDE_B 524288

// Output layout (floats)
#define Q_OFF     0
#define LOSS_OFF  16777216
#define IDX_OFF   16777217
#define NEMB_OFF  16908289
#define NCS_OFF   16973825
#define NEA_OFF   16974337

// Workspace layout (floats). e_hiP/e_loP OVERLAY the esum region: k_prep writes
// them, k_assign reads them, then esum is memset to 0 before k_ema2 uses it.
#define WS_E2    0
#define WS_ENC   512
#define WS_ESUM  1024
#define WS_EHI   1024          // f16[K*DIM] = 32768 floats
#define WS_ELO   33792         // f16[K*DIM] = 32768 floats (ends at 66560)
#define WS_LOSS  66560
#define WS_NN    66561

#define XST 136   // xs row stride (f16): 128 d + 8 pad -> 272B, 16B-aligned, 2-way banks

// ---------------------------------------------------------------------------
// k_prep: split codebook into f16 hi/lo in a FRAGMENT-LINEAR packed layout:
//   element e[c][dd]  (c = code 0..511, dd = 0..127)
//   g = c>>4, r = c&15, dc = dd>>5, quad = (dd>>3)&3, j = dd&7
//   packed[(g*4+dc)*512 + quad*128 + r*8 + j]
// With this layout, the B-fragment load for a 16x16x32 MFMA tile
// (codes g*16..g*16+15, k-chunk dc) is 64 lanes x 16B fully CONTIGUOUS (1KB).
__global__ __launch_bounds__(256) void k_prep(const float* __restrict__ emb,
                                              f16* __restrict__ ehiP,
                                              f16* __restrict__ eloP) {
    int lin = blockIdx.x * 256 + threadIdx.x;   // 65536 threads
    int d = lin >> 9, k = lin & 511;
    float v = emb[lin];                          // coalesced read
    f16 h = (f16)v;
    f16 l = (f16)(v - (float)h);
    int g = k >> 4, r = k & 15;
    int dc = d >> 5, w = d & 31, quad = w >> 3, j = w & 7;
    int idx = (g * 4 + dc) * 512 + quad * 128 + r * 8 + j;
    ehiP[idx] = h;                               // scattered 2B writes (one-shot, tiny)
    eloP[idx] = l;
}

// ---------------------------------------------------------------------------
// k_e2: exact fp32 per-code squared norms. 8 blocks x 256 (4 d-quarters x 64 codes).
__global__ __launch_bounds__(256) void k_e2(const float* __restrict__ emb,
                                            float* __restrict__ e2) {
    __shared__ float part[4][64];
    int kk = blockIdx.x * 64 + (threadIdx.x & 63);
    int dq = threadIdx.x >> 6;
    float s = 0.f;
    #pragma unroll 8
    for (int d = dq * 32; d < dq * 32 + 32; ++d) {
        float v = emb[d * K + kk];
        s = fmaf(v, v, s);
    }
    part[dq][threadIdx.x & 63] = s;
    __syncthreads();
    if (threadIdx.x < 64)
        e2[blockIdx.x * 64 + threadIdx.x] =
            part[0][threadIdx.x] + part[1][threadIdx.x] +
            part[2][threadIdx.x] + part[3][threadIdx.x];
}

// ---------------------------------------------------------------------------
// k_assign (MFMA): 64 positions/block, all 512 codes, D=128.
// score = e2[c] - 2*dot(x,e); dot via 3-pass f16-split MFMA (hh + lh + hl).
// X staged in LDS once (single barrier); B fragments read DIRECTLY from the
// packed global codebook (L2-resident, fully coalesced 1KB/wave loads).
// No per-stage barriers; LDS = 37 KB -> 3-4 blocks/CU.
__global__ __launch_bounds__(256, 3) void k_assign(const float* __restrict__ z,
                                                   const float* __restrict__ emb,
                                                   const f16* __restrict__ ehiP,
                                                   const f16* __restrict__ eloP,
                                                   const float* __restrict__ e2,
                                                   float* __restrict__ out,
                                                   float* __restrict__ lossAcc) {
    __shared__ f16 xs_h[64 * XST];
    __shared__ f16 xs_l[64 * XST];
    __shared__ float wbD[256];
    __shared__ int   wbI[256];
    __shared__ int   bidx[64];
    __shared__ float wred[4];

    const int tid  = threadIdx.x;
    const int lane = tid & 63;
    const int wv   = tid >> 6;
    const int n0   = blockIdx.x * 64;
    const int b    = n0 >> 12;
    const int hw0  = n0 & 4095;
    const float* zb = z + b * ZSTRIDE_B + hw0;
    const int l15  = lane & 15;
    const int quad = lane >> 4;

    // ---- stage X split (64 pos x 128 d), d-pair packed u32 LDS writes
    #pragma unroll
    for (int it = 0; it < 16; ++it) {
        int lin = tid + it * 256;
        int i  = lin & 63;          // position (lanes consecutive -> coalesced)
        int dp = lin >> 6;          // d-pair 0..63
        float v0 = zb[(2 * dp) * HW + i];
        float v1 = zb[(2 * dp + 1) * HW + i];
        f16 h0 = (f16)v0; f16 l0 = (f16)(v0 - (float)h0);
        f16 h1 = (f16)v1; f16 l1 = (f16)(v1 - (float)h1);
        union { f16 h[2]; unsigned int u; } ph, pl;
        ph.h[0] = h0; ph.h[1] = h1;
        pl.h[0] = l0; pl.h[1] = l1;
        *(unsigned int*)&xs_h[i * XST + 2 * dp] = ph.u;
        *(unsigned int*)&xs_l[i * XST + 2 * dp] = pl.u;
    }
    __syncthreads();

    float bestD[4][4];
    int   bestI[4][4];
    #pragma unroll
    for (int t = 0; t < 4; ++t)
        #pragma unroll
        for (int r = 0; r < 4; ++r) { bestD[t][r] = FLT_MAX; bestI[t][r] = 0x7fffffff; }

    const half8* gh = (const half8*)ehiP;
    const half8* gl = (const half8*)eloP;

    #pragma unroll
    for (int nc = 0; nc < 2; ++nc) {
        floatx4 acc[4][4];
        #pragma unroll
        for (int t = 0; t < 4; ++t)
            #pragma unroll
            for (int nt = 0; nt < 4; ++nt) acc[t][nt] = (floatx4){0.f, 0.f, 0.f, 0.f};

        #pragma unroll
        for (int dc = 0; dc < 4; ++dc) {
            // A fragments: A[m = t*16 + (lane&15)][k = quad*8 + j]
            half8 ah[4], al[4];
            #pragma unroll
            for (int t = 0; t < 4; ++t) {
                int off = (t * 16 + l15) * XST + dc * 32 + quad * 8;
                ah[t] = *(const half8*)&xs_h[off];
                al[t] = *(const half8*)&xs_l[off];
            }
            #pragma unroll
            for (int nt = 0; nt < 4; ++nt) {
                // B fragment: wave-contiguous 1KB load from packed codebook
                int bi = ((nc * 16 + wv * 4 + nt) * 4 + dc) * 64 + lane;
                half8 bh = gh[bi];
                half8 bl = gl[bi];
                #pragma unroll
                for (int t = 0; t < 4; ++t) {
                    acc[t][nt] = __builtin_amdgcn_mfma_f32_16x16x32_f16(ah[t], bh, acc[t][nt], 0, 0, 0);
                    acc[t][nt] = __builtin_amdgcn_mfma_f32_16x16x32_f16(al[t], bh, acc[t][nt], 0, 0, 0);
                    acc[t][nt] = __builtin_amdgcn_mfma_f32_16x16x32_f16(ah[t], bl, acc[t][nt], 0, 0, 0);
                }
            }
        }
        // fold scores into best (codes ascend across nc,nt for fixed lane -> strict <)
        #pragma unroll
        for (int nt = 0; nt < 4; ++nt) {
            int c = nc * 256 + wv * 64 + nt * 16 + l15;
            float ee = e2[c];
            #pragma unroll
            for (int t = 0; t < 4; ++t)
                #pragma unroll
                for (int r = 0; r < 4; ++r) {
                    float s = fmaf(-2.f, acc[t][nt][r], ee);
                    if (s < bestD[t][r]) { bestD[t][r] = s; bestI[t][r] = c; }
                }
        }
    }

    // reduce across the 16 lanes holding different codes for the same rows
    #pragma unroll
    for (int mask = 1; mask <= 8; mask <<= 1) {
        #pragma unroll
        for (int t = 0; t < 4; ++t)
            #pragma unroll
            for (int r = 0; r < 4; ++r) {
                float od = __shfl_xor(bestD[t][r], mask, 64);
                int   oi = __shfl_xor(bestI[t][r], mask, 64);
                if (od < bestD[t][r] || (od == bestD[t][r] && oi < bestI[t][r])) {
                    bestD[t][r] = od; bestI[t][r] = oi;
                }
            }
    }
    if (l15 == 0) {
        #pragma unroll
        for (int t = 0; t < 4; ++t)
            #pragma unroll
            for (int r = 0; r < 4; ++r) {
                int m = t * 16 + quad * 4 + r;   // C layout: row=(lane>>4)*4+reg
                wbD[wv * 64 + m] = bestD[t][r];
                wbI[wv * 64 + m] = bestI[t][r];
            }
    }
    __syncthreads();
    if (tid < 64) {
        float bd = wbD[tid]; int bi = wbI[tid];
        #pragma unroll
        for (int w = 1; w < 4; ++w) {
            float od = wbD[w * 64 + tid]; int oi = wbI[w * 64 + tid];
            if (od < bd || (od == bd && oi < bi)) { bd = od; bi = oi; }
        }
        bidx[tid] = bi;
        out[IDX_OFF + n0 + tid] = (float)bi;
    }
    __syncthreads();

    // epilogue: quantized output (exact fp32 codebook gather) + loss partial
    float lsum = 0.f;
    #pragma unroll 4
    for (int r = 0; r < 32; ++r) {
        int lin = tid + r * 256;
        int d = lin >> 6, i = lin & 63;
        float q  = emb[d * K + bidx[i]];
        float zz = zb[d * HW + i];
        out[Q_OFF + b * ZSTRIDE_B + d * HW + hw0 + i] = q;
        float df = q - zz;
        lsum = fmaf(df, df, lsum);
    }
    #pragma unroll
    for (int m = 32; m >= 1; m >>= 1) lsum += __shfl_xor(lsum, m, 64);
    if ((tid & 63) == 0) wred[wv] = lsum;
    __syncthreads();
    if (tid == 0) {
        float t = wred[0] + wred[1] + wred[2] + wred[3];
        atomicAdd(lossAcc, t);
    }
}

// ---------------------------------------------------------------------------
// k_ema2: LDS-privatized segment sums. 512 blocks (32 batches x 16 d-chunks).
#define DC 8
__global__ __launch_bounds__(256) void k_ema2(const float* __restrict__ z,
                                              const float* __restrict__ out,
                                              float* __restrict__ enc,
                                              float* __restrict__ esum) {
    __shared__ float acc[DC][K];   // 16 KB
    __shared__ float cnt[K];       // 2 KB

    const int tid = threadIdx.x;
    const int dchunk = blockIdx.x & 15;
    const int b      = blockIdx.x >> 4;
    const int d0 = dchunk * DC;
    const bool doCnt = (dchunk == 0);

    for (int i = tid; i < DC * K; i += 256) ((float*)acc)[i] = 0.f;
    if (doCnt) for (int i = tid; i < K; i += 256) cnt[i] = 0.f;
    __syncthreads();

    const float* zb  = z + b * ZSTRIDE_B;
    const float* idp = out + IDX_OFF + b * HW;
    for (int t = 0; t < HW; t += 1024) {
        const int p = t + 4 * tid;
        int k0 = (int)idp[p + 0];
        int k1 = (int)idp[p + 1];
        int k2 = (int)idp[p + 2];
        int k3 = (int)idp[p + 3];
        if (doCnt) {
            atomicAdd(&cnt[k0], 1.f); atomicAdd(&cnt[k1], 1.f);
            atomicAdd(&cnt[k2], 1.f); atomicAdd(&cnt[k3], 1.f);
        }
        #pragma unroll
        for (int d = 0; d < DC; ++d) {
            float4 zv = *(const float4*)(zb + (d0 + d) * HW + p);
            atomicAdd(&acc[d][k0], zv.x);
            atomicAdd(&acc[d][k1], zv.y);
            atomicAdd(&acc[d][k2], zv.z);
            atomicAdd(&acc[d][k3], zv.w);
        }
    }
    __syncthreads();

    for (int i = tid; i < DC * K; i += 256) {
        int d = i >> 9, k = i & 511;
        atomicAdd(&esum[(d0 + d) * K + k], acc[d][k]);
    }
    if (doCnt) for (int i = tid; i < K; i += 256) atomicAdd(&enc[i], cnt[i]);
}

// ---------------------------------------------------------------------------
// k_final: scalar part only (ncs, n, loss). 1 block.
__global__ __launch_bounds__(512) void k_final(const float* __restrict__ enc,
                                               const float* __restrict__ cs_in,
                                               const float* __restrict__ lossAcc,
                                               float* __restrict__ out,
                                               float* __restrict__ nnOut) {
    __shared__ float red[512];
    int k = threadIdx.x;
    float ncs = fmaf(cs_in[k], 0.99f, 0.01f * enc[k]);
    red[k] = ncs;
    out[NCS_OFF + k] = ncs;
    __syncthreads();
    for (int s = 256; s > 0; s >>= 1) {
        if (k < s) red[k] += red[k + s];
        __syncthreads();
    }
    if (k == 0) {
        nnOut[0] = fmaxf(red[0], 1e-5f);
        out[LOSS_OFF] = lossAcc[0] * 1.25f / 16777216.0f;
    }
}

// k_final2: embedding update, fully parallel (128 blocks = one per d), coalesced.
__global__ __launch_bounds__(512) void k_final2(const float* __restrict__ esum,
                                                const float* __restrict__ eavg_in,
                                                const float* __restrict__ nnIn,
                                                float* __restrict__ out) {
    int d = blockIdx.x;
    int k = threadIdx.x;
    float nn = nnIn[0];
    float ncs = out[NCS_OFF + k];
    float cs = (ncs + 1e-5f) / (nn + (float)K * 1e-5f) * nn;
    float ea = fmaf(eavg_in[d * K + k], 0.99f, 0.01f * esum[d * K + k]);
    out[NEA_OFF + d * K + k] = ea;
    out[NEMB_OFF + d * K + k] = ea / cs;
}

// ---------------------------------------------------------------------------
extern "C" void kernel_launch(void* const* d_in, const int* in_sizes, int n_in,
                              void* d_out, int out_size, void* d_ws, size_t ws_size,
                              hipStream_t stream) {
    const float* z     = (const float*)d_in[0];
    const float* emb   = (const float*)d_in[1];
    const float* cs_in = (const float*)d_in[2];
    const float* eavg  = (const float*)d_in[3];
    float* out = (float*)d_out;
    float* wsF = (float*)d_ws;

    hipMemsetAsync(wsF + WS_ENC, 0, 512 * sizeof(float), stream);
    hipMemsetAsync(wsF + WS_LOSS, 0, sizeof(float), stream);

    k_prep<<<256, 256, 0, stream>>>(emb, (f16*)(wsF + WS_EHI), (f16*)(wsF + WS_ELO));
    k_e2<<<8, 256, 0, stream>>>(emb, wsF + WS_E2);
    k_assign<<<NPOS / 64, 256, 0, stream>>>(z, emb,
                                            (const f16*)(wsF + WS_EHI),
                                            (const f16*)(wsF + WS_ELO),
                                            wsF + WS_E2, out, wsF + WS_LOSS);
    // e_hiP/e_loP no longer needed: reclaim region as esum
    hipMemsetAsync(wsF + WS_ESUM, 0, 65536 * sizeof(float), stream);
    k_ema2<<<512, 256, 0, stream>>>(z, out, wsF + WS_ENC, wsF + WS_ESUM);
    k_final<<<1, 512, 0, stream>>>(wsF + WS_ENC, cs_in, wsF + WS_LOSS,
                                   out, wsF + WS_NN);
    k_final2<<<128, 512, 0, stream>>>(wsF + WS_ESUM, eavg, wsF + WS_NN, out);
}

// Round 2
// 354.241 us; speedup vs baseline: 1.2887x; 1.2887x over previous
//
#include <hip/hip_runtime.h>
#include <hip/hip_bf16.h>
#include <float.h>

typedef _Float16 f16;
typedef __attribute__((ext_vector_type(8))) _Float16 half8;
typedef __attribute__((ext_vector_type(4))) float floatx4;

// Problem constants
#define DIM   128
#define HW    4096
#define NPOS  131072
#define K     512
#define ZSTRIDE_B 524288

// Output layout (floats)
#define Q_OFF     0
#define LOSS_OFF  16777216
#define IDX_OFF   16777217
#define NEMB_OFF  16908289
#define NCS_OFF   16973825
#define NEA_OFF   16974337

// Workspace layout (floats). e_hiP/e_loP OVERLAY the esum region: k_prep writes
// them, k_assign reads them, then esum is memset to 0 before k_ema2 uses it.
#define WS_E2    0
#define WS_ENC   512
#define WS_ESUM  1024
#define WS_EHI   1024          // f16[K*DIM] = 32768 floats
#define WS_ELO   33792         // f16[K*DIM] = 32768 floats (ends at 66560)
#define WS_LOSS  66560
#define WS_NN    66561

#define XST 136   // xs row stride (f16): 128 d + 8 pad -> 272B, 16B-aligned, 2-way banks

// ---------------------------------------------------------------------------
// k_prep: split codebook into f16 hi/lo in a FRAGMENT-LINEAR packed layout:
//   element e[c][dd]  (c = code 0..511, dd = 0..127)
//   g = c>>4, r = c&15, dc = dd>>5, quad = (dd>>3)&3, j = dd&7
//   packed[(g*4+dc)*512 + quad*128 + r*8 + j]
// With this layout, the B-fragment load for a 16x16x32 MFMA tile
// (codes g*16..g*16+15, k-chunk dc) is 64 lanes x 16B fully CONTIGUOUS (1KB).
__global__ __launch_bounds__(256) void k_prep(const float* __restrict__ emb,
                                              f16* __restrict__ ehiP,
                                              f16* __restrict__ eloP) {
    int lin = blockIdx.x * 256 + threadIdx.x;   // 65536 threads
    int d = lin >> 9, k = lin & 511;
    float v = emb[lin];                          // coalesced read
    f16 h = (f16)v;
    f16 l = (f16)(v - (float)h);
    int g = k >> 4, r = k & 15;
    int dc = d >> 5, w = d & 31, quad = w >> 3, j = w & 7;
    int idx = (g * 4 + dc) * 512 + quad * 128 + r * 8 + j;
    ehiP[idx] = h;                               // scattered 2B writes (one-shot, tiny)
    eloP[idx] = l;
}

// ---------------------------------------------------------------------------
// k_e2: exact fp32 per-code squared norms. 8 blocks x 256 (4 d-quarters x 64 codes).
__global__ __launch_bounds__(256) void k_e2(const float* __restrict__ emb,
                                            float* __restrict__ e2) {
    __shared__ float part[4][64];
    int kk = blockIdx.x * 64 + (threadIdx.x & 63);
    int dq = threadIdx.x >> 6;
    float s = 0.f;
    #pragma unroll 8
    for (int d = dq * 32; d < dq * 32 + 32; ++d) {
        float v = emb[d * K + kk];
        s = fmaf(v, v, s);
    }
    part[dq][threadIdx.x & 63] = s;
    __syncthreads();
    if (threadIdx.x < 64)
        e2[blockIdx.x * 64 + threadIdx.x] =
            part[0][threadIdx.x] + part[1][threadIdx.x] +
            part[2][threadIdx.x] + part[3][threadIdx.x];
}

// ---------------------------------------------------------------------------
// k_assign (MFMA): 64 positions/block, all 512 codes, D=128.
// score = e2[c] - 2*dot(x,e); dot via 3-pass f16-split MFMA (hh + lh + hl).
// X staged in LDS once (single barrier); B fragments read DIRECTLY from the
// packed global codebook (L2-resident, fully coalesced 1KB/wave loads).
// NOTE: no occupancy pin -- (256,3) in a previous attempt forced VGPR=84 and
// the accumulators spilled to scratch (+540MB HBM writes). Plain bounds give
// ~156 VGPRs, spill-free (verified by round-0 twin of this register set).
__global__ __launch_bounds__(256) void k_assign(const float* __restrict__ z,
                                                const float* __restrict__ emb,
                                                const f16* __restrict__ ehiP,
                                                const f16* __restrict__ eloP,
                                                const float* __restrict__ e2,
                                                float* __restrict__ out,
                                                float* __restrict__ lossAcc) {
    __shared__ f16 xs_h[64 * XST];
    __shared__ f16 xs_l[64 * XST];
    __shared__ float wbD[256];
    __shared__ int   wbI[256];
    __shared__ int   bidx[64];
    __shared__ float wred[4];

    const int tid  = threadIdx.x;
    const int lane = tid & 63;
    const int wv   = tid >> 6;
    const int n0   = blockIdx.x * 64;
    const int b    = n0 >> 12;
    const int hw0  = n0 & 4095;
    const float* zb = z + b * ZSTRIDE_B + hw0;
    const int l15  = lane & 15;
    const int quad = lane >> 4;

    // ---- stage X split (64 pos x 128 d), d-pair packed u32 LDS writes
    #pragma unroll
    for (int it = 0; it < 16; ++it) {
        int lin = tid + it * 256;
        int i  = lin & 63;          // position (lanes consecutive -> coalesced)
        int dp = lin >> 6;          // d-pair 0..63
        float v0 = zb[(2 * dp) * HW + i];
        float v1 = zb[(2 * dp + 1) * HW + i];
        f16 h0 = (f16)v0; f16 l0 = (f16)(v0 - (float)h0);
        f16 h1 = (f16)v1; f16 l1 = (f16)(v1 - (float)h1);
        union { f16 h[2]; unsigned int u; } ph, pl;
        ph.h[0] = h0; ph.h[1] = h1;
        pl.h[0] = l0; pl.h[1] = l1;
        *(unsigned int*)&xs_h[i * XST + 2 * dp] = ph.u;
        *(unsigned int*)&xs_l[i * XST + 2 * dp] = pl.u;
    }
    __syncthreads();

    float bestD[4][4];
    int   bestI[4][4];
    #pragma unroll
    for (int t = 0; t < 4; ++t)
        #pragma unroll
        for (int r = 0; r < 4; ++r) { bestD[t][r] = FLT_MAX; bestI[t][r] = 0x7fffffff; }

    const half8* gh = (const half8*)ehiP;
    const half8* gl = (const half8*)eloP;

    for (int nc = 0; nc < 2; ++nc) {
        floatx4 acc[4][4];
        #pragma unroll
        for (int t = 0; t < 4; ++t)
            #pragma unroll
            for (int nt = 0; nt < 4; ++nt) acc[t][nt] = (floatx4){0.f, 0.f, 0.f, 0.f};

        for (int dc = 0; dc < 4; ++dc) {
            // A fragments: A[m = t*16 + (lane&15)][k = quad*8 + j]
            half8 ah[4], al[4];
            #pragma unroll
            for (int t = 0; t < 4; ++t) {
                int off = (t * 16 + l15) * XST + dc * 32 + quad * 8;
                ah[t] = *(const half8*)&xs_h[off];
                al[t] = *(const half8*)&xs_l[off];
            }
            #pragma unroll
            for (int nt = 0; nt < 4; ++nt) {
                // B fragment: wave-contiguous 1KB load from packed codebook
                int bi = ((nc * 16 + wv * 4 + nt) * 4 + dc) * 64 + lane;
                half8 bh = gh[bi];
                half8 bl = gl[bi];
                #pragma unroll
                for (int t = 0; t < 4; ++t) {
                    acc[t][nt] = __builtin_amdgcn_mfma_f32_16x16x32_f16(ah[t], bh, acc[t][nt], 0, 0, 0);
                    acc[t][nt] = __builtin_amdgcn_mfma_f32_16x16x32_f16(al[t], bh, acc[t][nt], 0, 0, 0);
                    acc[t][nt] = __builtin_amdgcn_mfma_f32_16x16x32_f16(ah[t], bl, acc[t][nt], 0, 0, 0);
                }
            }
        }
        // fold scores into best (codes ascend across nc,nt for fixed lane -> strict <)
        #pragma unroll
        for (int nt = 0; nt < 4; ++nt) {
            int c = nc * 256 + wv * 64 + nt * 16 + l15;
            float ee = e2[c];
            #pragma unroll
            for (int t = 0; t < 4; ++t)
                #pragma unroll
                for (int r = 0; r < 4; ++r) {
                    float s = fmaf(-2.f, acc[t][nt][r], ee);
                    if (s < bestD[t][r]) { bestD[t][r] = s; bestI[t][r] = c; }
                }
        }
    }

    // reduce across the 16 lanes holding different codes for the same rows
    #pragma unroll
    for (int mask = 1; mask <= 8; mask <<= 1) {
        #pragma unroll
        for (int t = 0; t < 4; ++t)
            #pragma unroll
            for (int r = 0; r < 4; ++r) {
                float od = __shfl_xor(bestD[t][r], mask, 64);
                int   oi = __shfl_xor(bestI[t][r], mask, 64);
                if (od < bestD[t][r] || (od == bestD[t][r] && oi < bestI[t][r])) {
                    bestD[t][r] = od; bestI[t][r] = oi;
                }
            }
    }
    if (l15 == 0) {
        #pragma unroll
        for (int t = 0; t < 4; ++t)
            #pragma unroll
            for (int r = 0; r < 4; ++r) {
                int m = t * 16 + quad * 4 + r;   // C layout: row=(lane>>4)*4+reg
                wbD[wv * 64 + m] = bestD[t][r];
                wbI[wv * 64 + m] = bestI[t][r];
            }
    }
    __syncthreads();
    if (tid < 64) {
        float bd = wbD[tid]; int bi = wbI[tid];
        #pragma unroll
        for (int w = 1; w < 4; ++w) {
            float od = wbD[w * 64 + tid]; int oi = wbI[w * 64 + tid];
            if (od < bd || (od == bd && oi < bi)) { bd = od; bi = oi; }
        }
        bidx[tid] = bi;
        out[IDX_OFF + n0 + tid] = (float)bi;
    }
    __syncthreads();

    // epilogue: quantized output (exact fp32 codebook gather) + loss partial
    float lsum = 0.f;
    #pragma unroll 4
    for (int r = 0; r < 32; ++r) {
        int lin = tid + r * 256;
        int d = lin >> 6, i = lin & 63;
        float q  = emb[d * K + bidx[i]];
        float zz = zb[d * HW + i];
        out[Q_OFF + b * ZSTRIDE_B + d * HW + hw0 + i] = q;
        float df = q - zz;
        lsum = fmaf(df, df, lsum);
    }
    #pragma unroll
    for (int m = 32; m >= 1; m >>= 1) lsum += __shfl_xor(lsum, m, 64);
    if ((tid & 63) == 0) wred[wv] = lsum;
    __syncthreads();
    if (tid == 0) {
        float t = wred[0] + wred[1] + wred[2] + wred[3];
        atomicAdd(lossAcc, t);
    }
}

// ---------------------------------------------------------------------------
// k_ema2: LDS-privatized segment sums. 512 blocks (32 batches x 16 d-chunks).
#define DC 8
__global__ __launch_bounds__(256) void k_ema2(const float* __restrict__ z,
                                              const float* __restrict__ out,
                                              float* __restrict__ enc,
                                              float* __restrict__ esum) {
    __shared__ float acc[DC][K];   // 16 KB
    __shared__ float cnt[K];       // 2 KB

    const int tid = threadIdx.x;
    const int dchunk = blockIdx.x & 15;
    const int b      = blockIdx.x >> 4;
    const int d0 = dchunk * DC;
    const bool doCnt = (dchunk == 0);

    for (int i = tid; i < DC * K; i += 256) ((float*)acc)[i] = 0.f;
    if (doCnt) for (int i = tid; i < K; i += 256) cnt[i] = 0.f;
    __syncthreads();

    const float* zb  = z + b * ZSTRIDE_B;
    const float* idp = out + IDX_OFF + b * HW;
    for (int t = 0; t < HW; t += 1024) {
        const int p = t + 4 * tid;
        int k0 = (int)idp[p + 0];
        int k1 = (int)idp[p + 1];
        int k2 = (int)idp[p + 2];
        int k3 = (int)idp[p + 3];
        if (doCnt) {
            atomicAdd(&cnt[k0], 1.f); atomicAdd(&cnt[k1], 1.f);
            atomicAdd(&cnt[k2], 1.f); atomicAdd(&cnt[k3], 1.f);
        }
        #pragma unroll
        for (int d = 0; d < DC; ++d) {
            float4 zv = *(const float4*)(zb + (d0 + d) * HW + p);
            atomicAdd(&acc[d][k0], zv.x);
            atomicAdd(&acc[d][k1], zv.y);
            atomicAdd(&acc[d][k2], zv.z);
            atomicAdd(&acc[d][k3], zv.w);
        }
    }
    __syncthreads();

    for (int i = tid; i < DC * K; i += 256) {
        int d = i >> 9, k = i & 511;
        atomicAdd(&esum[(d0 + d) * K + k], acc[d][k]);
    }
    if (doCnt) for (int i = tid; i < K; i += 256) atomicAdd(&enc[i], cnt[i]);
}

// ---------------------------------------------------------------------------
// k_final: scalar part only (ncs, n, loss). 1 block.
__global__ __launch_bounds__(512) void k_final(const float* __restrict__ enc,
                                               const float* __restrict__ cs_in,
                                               const float* __restrict__ lossAcc,
                                               float* __restrict__ out,
                                               float* __restrict__ nnOut) {
    __shared__ float red[512];
    int k = threadIdx.x;
    float ncs = fmaf(cs_in[k], 0.99f, 0.01f * enc[k]);
    red[k] = ncs;
    out[NCS_OFF + k] = ncs;
    __syncthreads();
    for (int s = 256; s > 0; s >>= 1) {
        if (k < s) red[k] += red[k + s];
        __syncthreads();
    }
    if (k == 0) {
        nnOut[0] = fmaxf(red[0], 1e-5f);
        out[LOSS_OFF] = lossAcc[0] * 1.25f / 16777216.0f;
    }
}

// k_final2: embedding update, fully parallel (128 blocks = one per d), coalesced.
__global__ __launch_bounds__(512) void k_final2(const float* __restrict__ esum,
                                                const float* __restrict__ eavg_in,
                                                const float* __restrict__ nnIn,
                                                float* __restrict__ out) {
    int d = blockIdx.x;
    int k = threadIdx.x;
    float nn = nnIn[0];
    float ncs = out[NCS_OFF + k];
    float cs = (ncs + 1e-5f) / (nn + (float)K * 1e-5f) * nn;
    float ea = fmaf(eavg_in[d * K + k], 0.99f, 0.01f * esum[d * K + k]);
    out[NEA_OFF + d * K + k] = ea;
    out[NEMB_OFF + d * K + k] = ea / cs;
}

// ---------------------------------------------------------------------------
extern "C" void kernel_launch(void* const* d_in, const int* in_sizes, int n_in,
                              void* d_out, int out_size, void* d_ws, size_t ws_size,
                              hipStream_t stream) {
    const float* z     = (const float*)d_in[0];
    const float* emb   = (const float*)d_in[1];
    const float* cs_in = (const float*)d_in[2];
    const float* eavg  = (const float*)d_in[3];
    float* out = (float*)d_out;
    float* wsF = (float*)d_ws;

    hipMemsetAsync(wsF + WS_ENC, 0, 512 * sizeof(float), stream);
    hipMemsetAsync(wsF + WS_LOSS, 0, sizeof(float), stream);

    k_prep<<<256, 256, 0, stream>>>(emb, (f16*)(wsF + WS_EHI), (f16*)(wsF + WS_ELO));
    k_e2<<<8, 256, 0, stream>>>(emb, wsF + WS_E2);
    k_assign<<<NPOS / 64, 256, 0, stream>>>(z, emb,
                                            (const f16*)(wsF + WS_EHI),
                                            (const f16*)(wsF + WS_ELO),
                                            wsF + WS_E2, out, wsF + WS_LOSS);
    // e_hiP/e_loP no longer needed: reclaim region as esum
    hipMemsetAsync(wsF + WS_ESUM, 0, 65536 * sizeof(float), stream);
    k_ema2<<<512, 256, 0, stream>>>(z, out, wsF + WS_ENC, wsF + WS_ESUM);
    k_final<<<1, 512, 0, stream>>>(wsF + WS_ENC, cs_in, wsF + WS_LOSS,
                                   out, wsF + WS_NN);
    k_final2<<<128, 512, 0, stream>>>(wsF + WS_ESUM, eavg, wsF + WS_NN, out);
}

// Round 3
// 330.633 us; speedup vs baseline: 1.3807x; 1.0714x over previous
//
#include <hip/hip_runtime.h>
#include <hip/hip_bf16.h>
#include <float.h>

typedef _Float16 f16;
typedef __attribute__((ext_vector_type(8))) _Float16 half8;
typedef __attribute__((ext_vector_type(4))) float floatx4;

// Problem constants
#define DIM   128
#define HW    4096
#define NPOS  131072
#define K     512
#define ZSTRIDE_B 524288

// Output layout (floats)
#define Q_OFF     0
#define LOSS_OFF  16777216
#define IDX_OFF   16777217
#define NEMB_OFF  16908289
#define NCS_OFF   16973825
#define NEA_OFF   16974337

// Workspace layout (floats). e_hiP/e_loP OVERLAY the esum region: k_prep writes
// them, k_assign reads them, then esum is memset to 0 before k_ema2 uses it.
#define WS_E2    0
#define WS_ENC   512
#define WS_ESUM  1024
#define WS_EHI   1024          // f16[K*DIM] = 32768 floats
#define WS_ELO   33792         // f16[K*DIM] = 32768 floats (ends at 66560)
#define WS_LOSS  66560
#define WS_NN    66561

#define XST 136   // xs row stride (f16): 128 d + 8 pad -> 272B, 16B-aligned, 2-way banks

// ---------------------------------------------------------------------------
// k_prep: split codebook into f16 hi/lo in a FRAGMENT-LINEAR packed layout
// (see round-1 comment), PLUS fused e2 computation via global atomics
// (E2 must be zeroed first; 128 atomics/address, ~µs-scale).
__global__ __launch_bounds__(256) void k_prep(const float* __restrict__ emb,
                                              f16* __restrict__ ehiP,
                                              f16* __restrict__ eloP,
                                              float* __restrict__ e2) {
    int lin = blockIdx.x * 256 + threadIdx.x;   // 65536 threads
    int d = lin >> 9, k = lin & 511;
    float v = emb[lin];                          // coalesced read
    atomicAdd(&e2[k], v * v);                    // fused squared-norm partial
    f16 h = (f16)v;
    f16 l = (f16)(v - (float)h);
    int g = k >> 4, r = k & 15;
    int dc = d >> 5, w = d & 31, quad = w >> 3, j = w & 7;
    int idx = (g * 4 + dc) * 512 + quad * 128 + r * 8 + j;
    ehiP[idx] = h;                               // scattered 2B writes (one-shot, tiny)
    eloP[idx] = l;
}

// ---------------------------------------------------------------------------
// k_assign (MFMA): 64 positions/block, all 512 codes, D=128.
// score = e2[c] - 2*dot(x,e); dot via 3-pass f16-split MFMA (hh + lh + hl).
// X staged in LDS once (single barrier); B fragments read DIRECTLY from the
// packed global codebook (L2-resident, fully coalesced 1KB/wave loads).
// EPILOGUE REMOVED: writes idx only. The Q gather/store/loss moved to k_ema2
// (the per-lane-random emb gather was ~2048 split transactions per wave here).
// NOTE: no occupancy pin -- (256,3) previously forced VGPR=84 + acc spill
// (+540MB scratch traffic). Plain bounds -> ~168 VGPR, spill-free.
__global__ __launch_bounds__(256) void k_assign(const float* __restrict__ z,
                                                const f16* __restrict__ ehiP,
                                                const f16* __restrict__ eloP,
                                                const float* __restrict__ e2,
                                                float* __restrict__ out) {
    __shared__ f16 xs_h[64 * XST];
    __shared__ f16 xs_l[64 * XST];
    __shared__ float wbD[256];
    __shared__ int   wbI[256];

    const int tid  = threadIdx.x;
    const int lane = tid & 63;
    const int wv   = tid >> 6;
    const int n0   = blockIdx.x * 64;
    const int b    = n0 >> 12;
    const int hw0  = n0 & 4095;
    const float* zb = z + b * ZSTRIDE_B + hw0;
    const int l15  = lane & 15;
    const int quad = lane >> 4;

    // ---- stage X split (64 pos x 128 d), d-pair packed u32 LDS writes
    #pragma unroll
    for (int it = 0; it < 16; ++it) {
        int lin = tid + it * 256;
        int i  = lin & 63;          // position (lanes consecutive -> coalesced)
        int dp = lin >> 6;          // d-pair 0..63
        float v0 = zb[(2 * dp) * HW + i];
        float v1 = zb[(2 * dp + 1) * HW + i];
        f16 h0 = (f16)v0; f16 l0 = (f16)(v0 - (float)h0);
        f16 h1 = (f16)v1; f16 l1 = (f16)(v1 - (float)h1);
        union { f16 h[2]; unsigned int u; } ph, pl;
        ph.h[0] = h0; ph.h[1] = h1;
        pl.h[0] = l0; pl.h[1] = l1;
        *(unsigned int*)&xs_h[i * XST + 2 * dp] = ph.u;
        *(unsigned int*)&xs_l[i * XST + 2 * dp] = pl.u;
    }
    __syncthreads();

    float bestD[4][4];
    int   bestI[4][4];
    #pragma unroll
    for (int t = 0; t < 4; ++t)
        #pragma unroll
        for (int r = 0; r < 4; ++r) { bestD[t][r] = FLT_MAX; bestI[t][r] = 0x7fffffff; }

    const half8* gh = (const half8*)ehiP;
    const half8* gl = (const half8*)eloP;

    for (int nc = 0; nc < 2; ++nc) {
        floatx4 acc[4][4];
        #pragma unroll
        for (int t = 0; t < 4; ++t)
            #pragma unroll
            for (int nt = 0; nt < 4; ++nt) acc[t][nt] = (floatx4){0.f, 0.f, 0.f, 0.f};

        for (int dc = 0; dc < 4; ++dc) {
            // A fragments: A[m = t*16 + (lane&15)][k = quad*8 + j]
            half8 ah[4], al[4];
            #pragma unroll
            for (int t = 0; t < 4; ++t) {
                int off = (t * 16 + l15) * XST + dc * 32 + quad * 8;
                ah[t] = *(const half8*)&xs_h[off];
                al[t] = *(const half8*)&xs_l[off];
            }
            #pragma unroll
            for (int nt = 0; nt < 4; ++nt) {
                // B fragment: wave-contiguous 1KB load from packed codebook
                int bi = ((nc * 16 + wv * 4 + nt) * 4 + dc) * 64 + lane;
                half8 bh = gh[bi];
                half8 bl = gl[bi];
                #pragma unroll
                for (int t = 0; t < 4; ++t) {
                    acc[t][nt] = __builtin_amdgcn_mfma_f32_16x16x32_f16(ah[t], bh, acc[t][nt], 0, 0, 0);
                    acc[t][nt] = __builtin_amdgcn_mfma_f32_16x16x32_f16(al[t], bh, acc[t][nt], 0, 0, 0);
                    acc[t][nt] = __builtin_amdgcn_mfma_f32_16x16x32_f16(ah[t], bl, acc[t][nt], 0, 0, 0);
                }
            }
        }
        // fold scores into best (codes ascend across nc,nt for fixed lane -> strict <)
        #pragma unroll
        for (int nt = 0; nt < 4; ++nt) {
            int c = nc * 256 + wv * 64 + nt * 16 + l15;
            float ee = e2[c];
            #pragma unroll
            for (int t = 0; t < 4; ++t)
                #pragma unroll
                for (int r = 0; r < 4; ++r) {
                    float s = fmaf(-2.f, acc[t][nt][r], ee);
                    if (s < bestD[t][r]) { bestD[t][r] = s; bestI[t][r] = c; }
                }
        }
    }

    // reduce across the 16 lanes holding different codes for the same rows
    #pragma unroll
    for (int mask = 1; mask <= 8; mask <<= 1) {
        #pragma unroll
        for (int t = 0; t < 4; ++t)
            #pragma unroll
            for (int r = 0; r < 4; ++r) {
                float od = __shfl_xor(bestD[t][r], mask, 64);
                int   oi = __shfl_xor(bestI[t][r], mask, 64);
                if (od < bestD[t][r] || (od == bestD[t][r] && oi < bestI[t][r])) {
                    bestD[t][r] = od; bestI[t][r] = oi;
                }
            }
    }
    if (l15 == 0) {
        #pragma unroll
        for (int t = 0; t < 4; ++t)
            #pragma unroll
            for (int r = 0; r < 4; ++r) {
                int m = t * 16 + quad * 4 + r;   // C layout: row=(lane>>4)*4+reg
                wbD[wv * 64 + m] = bestD[t][r];
                wbI[wv * 64 + m] = bestI[t][r];
            }
    }
    __syncthreads();
    if (tid < 64) {
        float bd = wbD[tid]; int bi = wbI[tid];
        #pragma unroll
        for (int w = 1; w < 4; ++w) {
            float od = wbD[w * 64 + tid]; int oi = wbI[w * 64 + tid];
            if (od < bd || (od == bd && oi < bi)) { bd = od; bi = oi; }
        }
        out[IDX_OFF + n0 + tid] = (float)bi;
    }
}

// ---------------------------------------------------------------------------
// k_ema2: LDS-privatized segment sums + FUSED quantized-output/loss epilogue.
// 512 blocks (32 batches x 16 d-chunks). Block stages its 8 emb rows (16KB)
// in LDS, so the Q gather is an LDS lookup (no scattered global loads), and
// Q is written as coalesced float4 alongside the z stream it already reads.
#define DC 8
__global__ __launch_bounds__(256) void k_ema2(const float* __restrict__ z,
                                              const float* __restrict__ emb,
                                              float* __restrict__ out,
                                              float* __restrict__ enc,
                                              float* __restrict__ esum,
                                              float* __restrict__ lossAcc) {
    __shared__ float acc[DC][K];   // 16 KB
    __shared__ float embs[DC][K];  // 16 KB
    __shared__ float cnt[K];       // 2 KB
    __shared__ float wred[4];

    const int tid = threadIdx.x;
    const int lane = tid & 63;
    const int wv = tid >> 6;
    const int dchunk = blockIdx.x & 15;
    const int b      = blockIdx.x >> 4;
    const int d0 = dchunk * DC;
    const bool doCnt = (dchunk == 0);

    for (int i = tid; i < DC * K; i += 256) {
        ((float*)acc)[i] = 0.f;
        ((float*)embs)[i] = emb[d0 * K + i];   // coalesced 16KB stage
    }
    if (doCnt) for (int i = tid; i < K; i += 256) cnt[i] = 0.f;
    __syncthreads();

    const float* zb  = z + b * ZSTRIDE_B;
    const float* idp = out + IDX_OFF + b * HW;
    float* qb = out + Q_OFF + b * ZSTRIDE_B;
    float lsum = 0.f;

    for (int t = 0; t < HW; t += 1024) {
        const int p = t + 4 * tid;
        int k0 = (int)idp[p + 0];
        int k1 = (int)idp[p + 1];
        int k2 = (int)idp[p + 2];
        int k3 = (int)idp[p + 3];
        if (doCnt) {
            atomicAdd(&cnt[k0], 1.f); atomicAdd(&cnt[k1], 1.f);
            atomicAdd(&cnt[k2], 1.f); atomicAdd(&cnt[k3], 1.f);
        }
        #pragma unroll
        for (int d = 0; d < DC; ++d) {
            float4 zv = *(const float4*)(zb + (d0 + d) * HW + p);
            atomicAdd(&acc[d][k0], zv.x);
            atomicAdd(&acc[d][k1], zv.y);
            atomicAdd(&acc[d][k2], zv.z);
            atomicAdd(&acc[d][k3], zv.w);
            float4 qv;
            qv.x = embs[d][k0]; qv.y = embs[d][k1];
            qv.z = embs[d][k2]; qv.w = embs[d][k3];
            *(float4*)(qb + (d0 + d) * HW + p) = qv;
            float dx = qv.x - zv.x; lsum = fmaf(dx, dx, lsum);
            float dy = qv.y - zv.y; lsum = fmaf(dy, dy, lsum);
            float dz2 = qv.z - zv.z; lsum = fmaf(dz2, dz2, lsum);
            float dw = qv.w - zv.w; lsum = fmaf(dw, dw, lsum);
        }
    }

    // loss partial: wave reduce -> LDS -> one atomic per block
    #pragma unroll
    for (int m = 32; m >= 1; m >>= 1) lsum += __shfl_xor(lsum, m, 64);
    if (lane == 0) wred[wv] = lsum;
    __syncthreads();   // also guarantees all LDS atomics complete before flush
    if (tid == 0) atomicAdd(lossAcc, wred[0] + wred[1] + wred[2] + wred[3]);

    for (int i = tid; i < DC * K; i += 256) {
        int d = i >> 9, k = i & 511;
        atomicAdd(&esum[(d0 + d) * K + k], acc[d][k]);
    }
    if (doCnt) for (int i = tid; i < K; i += 256) atomicAdd(&enc[i], cnt[i]);
}

// ---------------------------------------------------------------------------
// k_final: scalar part only (ncs, n, loss). 1 block.
__global__ __launch_bounds__(512) void k_final(const float* __restrict__ enc,
                                               const float* __restrict__ cs_in,
                                               const float* __restrict__ lossAcc,
                                               float* __restrict__ out,
                                               float* __restrict__ nnOut) {
    __shared__ float red[512];
    int k = threadIdx.x;
    float ncs = fmaf(cs_in[k], 0.99f, 0.01f * enc[k]);
    red[k] = ncs;
    out[NCS_OFF + k] = ncs;
    __syncthreads();
    for (int s = 256; s > 0; s >>= 1) {
        if (k < s) red[k] += red[k + s];
        __syncthreads();
    }
    if (k == 0) {
        nnOut[0] = fmaxf(red[0], 1e-5f);
        out[LOSS_OFF] = lossAcc[0] * 1.25f / 16777216.0f;
    }
}

// k_final2: embedding update, fully parallel (128 blocks = one per d), coalesced.
__global__ __launch_bounds__(512) void k_final2(const float* __restrict__ esum,
                                                const float* __restrict__ eavg_in,
                                                const float* __restrict__ nnIn,
                                                float* __restrict__ out) {
    int d = blockIdx.x;
    int k = threadIdx.x;
    float nn = nnIn[0];
    float ncs = out[NCS_OFF + k];
    float cs = (ncs + 1e-5f) / (nn + (float)K * 1e-5f) * nn;
    float ea = fmaf(eavg_in[d * K + k], 0.99f, 0.01f * esum[d * K + k]);
    out[NEA_OFF + d * K + k] = ea;
    out[NEMB_OFF + d * K + k] = ea / cs;
}

// ---------------------------------------------------------------------------
extern "C" void kernel_launch(void* const* d_in, const int* in_sizes, int n_in,
                              void* d_out, int out_size, void* d_ws, size_t ws_size,
                              hipStream_t stream) {
    const float* z     = (const float*)d_in[0];
    const float* emb   = (const float*)d_in[1];
    const float* cs_in = (const float*)d_in[2];
    const float* eavg  = (const float*)d_in[3];
    float* out = (float*)d_out;
    float* wsF = (float*)d_ws;

    // E2 (512) + ENC (512) are contiguous: one memset
    hipMemsetAsync(wsF + WS_E2, 0, 1024 * sizeof(float), stream);
    hipMemsetAsync(wsF + WS_LOSS, 0, sizeof(float), stream);

    k_prep<<<256, 256, 0, stream>>>(emb, (f16*)(wsF + WS_EHI), (f16*)(wsF + WS_ELO),
                                    wsF + WS_E2);
    k_assign<<<NPOS / 64, 256, 0, stream>>>(z,
                                            (const f16*)(wsF + WS_EHI),
                                            (const f16*)(wsF + WS_ELO),
                                            wsF + WS_E2, out);
    // e_hiP/e_loP no longer needed: reclaim region as esum
    hipMemsetAsync(wsF + WS_ESUM, 0, 65536 * sizeof(float), stream);
    k_ema2<<<512, 256, 0, stream>>>(z, emb, out, wsF + WS_ENC, wsF + WS_ESUM,
                                    wsF + WS_LOSS);
    k_final<<<1, 512, 0, stream>>>(wsF + WS_ENC, cs_in, wsF + WS_LOSS,
                                   out, wsF + WS_NN);
    k_final2<<<128, 512, 0, stream>>>(wsF + WS_ESUM, eavg, wsF + WS_NN, out);
}

// Round 5
// 291.088 us; speedup vs baseline: 1.5683x; 1.1359x over previous
//
#include <hip/hip_runtime.h>
#include <hip/hip_bf16.h>
#include <float.h>

typedef _Float16 f16;
typedef __attribute__((ext_vector_type(8))) _Float16 half8;
typedef __attribute__((ext_vector_type(4))) float floatx4;

// Problem constants
#define DIM   128
#define HW    4096
#define NPOS  131072
#define K     512
#define ZSTRIDE_B 524288

// Output layout (floats)
#define Q_OFF     0
#define LOSS_OFF  16777216
#define IDX_OFF   16777217
#define NEMB_OFF  16908289
#define NCS_OFF   16973825
#define NEA_OFF   16974337

// Workspace layout (floats). e_hiP/e_loP OVERLAY the esum region: k_prep writes
// them, k_assign reads them, then esum is memset to 0 before k_ema2 uses it.
#define WS_E2    0
#define WS_ENC   512
#define WS_ESUM  1024
#define WS_EHI   1024          // f16[K*DIM] = 32768 floats
#define WS_ELO   33792         // f16[K*DIM] = 32768 floats (ends at 66560)
#define WS_LOSS  66560
#define WS_NN    66561

#define XST 136   // xs row stride (f16): 128 d + 8 pad -> 272B, 16B-aligned, 2-way banks

// ---------------------------------------------------------------------------
// k_prep: split codebook into f16 hi/lo in a FRAGMENT-LINEAR packed layout:
//   g = c>>4, r = c&15, dc = dd>>5, quad = (dd>>3)&3, j = dd&7
//   packed[(g*4+dc)*512 + quad*128 + r*8 + j]
// B-fragment load for a 16x16 code tile/k-chunk = 64 lanes x 16B CONTIGUOUS.
// Fused e2 via global atomics (E2 zeroed first; 64 distinct addrs/wave).
__global__ __launch_bounds__(256) void k_prep(const float* __restrict__ emb,
                                              f16* __restrict__ ehiP,
                                              f16* __restrict__ eloP,
                                              float* __restrict__ e2) {
    int lin = blockIdx.x * 256 + threadIdx.x;   // 65536 threads
    int d = lin >> 9, k = lin & 511;
    float v = emb[lin];                          // coalesced read
    atomicAdd(&e2[k], v * v);                    // fused squared-norm partial
    f16 h = (f16)v;
    f16 l = (f16)(v - (float)h);
    int g = k >> 4, r = k & 15;
    int dc = d >> 5, w = d & 31, quad = w >> 3, j = w & 7;
    int idx = (g * 4 + dc) * 512 + quad * 128 + r * 8 + j;
    ehiP[idx] = h;                               // scattered 2B writes (one-shot, tiny)
    eloP[idx] = l;
}

// ---------------------------------------------------------------------------
// k_assign (MFMA): 64 positions/block, all 512 codes, D=128.
// score = e2[c] - 2*dot(x,e); dot via 3-pass f16-split MFMA (hh + lh + hl).
// v4 restructure: 4 code-chunks of 128 (acc[4][2] = 32 VGPR instead of 64),
// live set ~120 regs -> pin (256,2) for the 128-VGPR cliff (4 waves/SIMD).
// Observed mapping r1: (256,3) -> 84 VGPR (512/6); so (256,2) -> 128 (512/4).
// Stage loop split load-all/convert-all so 32 global loads issue in one burst.
// TRIPWIRE: if this spills, WRITE_SIZE balloons past ~1 MB.
__global__ __launch_bounds__(256, 2) void k_assign(const float* __restrict__ z,
                                                   const f16* __restrict__ ehiP,
                                                   const f16* __restrict__ eloP,
                                                   const float* __restrict__ e2,
                                                   float* __restrict__ out) {
    __shared__ f16 xs_h[64 * XST];
    __shared__ f16 xs_l[64 * XST];
    __shared__ float wbD[256];
    __shared__ int   wbI[256];

    const int tid  = threadIdx.x;
    const int lane = tid & 63;
    const int wv   = tid >> 6;
    const int n0   = blockIdx.x * 64;
    const int b    = n0 >> 12;
    const int hw0  = n0 & 4095;
    const float* zb = z + b * ZSTRIDE_B + hw0;
    const int l15  = lane & 15;
    const int quad = lane >> 4;

    // ---- stage X split (64 pos x 128 d): phase 1 = issue all 32 loads,
    // phase 2 = convert + packed u32 LDS writes. Static indexing throughout.
    float sv0[16], sv1[16];
    #pragma unroll
    for (int it = 0; it < 16; ++it) {
        int lin = tid + it * 256;
        int i  = lin & 63;          // position (lanes consecutive -> coalesced)
        int dp = lin >> 6;          // d-pair 0..63
        sv0[it] = zb[(2 * dp) * HW + i];
        sv1[it] = zb[(2 * dp + 1) * HW + i];
    }
    #pragma unroll
    for (int it = 0; it < 16; ++it) {
        int lin = tid + it * 256;
        int i  = lin & 63;
        int dp = lin >> 6;
        float v0 = sv0[it], v1 = sv1[it];
        f16 h0 = (f16)v0; f16 l0 = (f16)(v0 - (float)h0);
        f16 h1 = (f16)v1; f16 l1 = (f16)(v1 - (float)h1);
        union { f16 h[2]; unsigned int u; } ph, pl;
        ph.h[0] = h0; ph.h[1] = h1;
        pl.h[0] = l0; pl.h[1] = l1;
        *(unsigned int*)&xs_h[i * XST + 2 * dp] = ph.u;
        *(unsigned int*)&xs_l[i * XST + 2 * dp] = pl.u;
    }
    __syncthreads();

    float bestD[4][4];
    int   bestI[4][4];
    #pragma unroll
    for (int t = 0; t < 4; ++t)
        #pragma unroll
        for (int r = 0; r < 4; ++r) { bestD[t][r] = FLT_MAX; bestI[t][r] = 0x7fffffff; }

    const half8* gh = (const half8*)ehiP;
    const half8* gl = (const half8*)eloP;

    for (int cc = 0; cc < 4; ++cc) {       // 4 chunks x 128 codes
        floatx4 acc[4][2];
        #pragma unroll
        for (int t = 0; t < 4; ++t)
            #pragma unroll
            for (int nt = 0; nt < 2; ++nt) acc[t][nt] = (floatx4){0.f, 0.f, 0.f, 0.f};

        for (int dc = 0; dc < 4; ++dc) {
            // A fragments: A[m = t*16 + (lane&15)][k = quad*8 + j]
            half8 ah[4], al[4];
            #pragma unroll
            for (int t = 0; t < 4; ++t) {
                int off = (t * 16 + l15) * XST + dc * 32 + quad * 8;
                ah[t] = *(const half8*)&xs_h[off];
                al[t] = *(const half8*)&xs_l[off];
            }
            #pragma unroll
            for (int nt = 0; nt < 2; ++nt) {
                // B fragment: wave-contiguous 1KB load from packed codebook
                int g  = cc * 8 + wv * 2 + nt;      // 16-code group
                int bi = (g * 4 + dc) * 64 + lane;
                half8 bh = gh[bi];
                half8 bl = gl[bi];
                #pragma unroll
                for (int t = 0; t < 4; ++t) {
                    acc[t][nt] = __builtin_amdgcn_mfma_f32_16x16x32_f16(ah[t], bh, acc[t][nt], 0, 0, 0);
                    acc[t][nt] = __builtin_amdgcn_mfma_f32_16x16x32_f16(al[t], bh, acc[t][nt], 0, 0, 0);
                    acc[t][nt] = __builtin_amdgcn_mfma_f32_16x16x32_f16(ah[t], bl, acc[t][nt], 0, 0, 0);
                }
            }
        }
        // fold scores into best (codes ascend across cc,nt for fixed lane -> strict <)
        #pragma unroll
        for (int nt = 0; nt < 2; ++nt) {
            int c = cc * 128 + wv * 32 + nt * 16 + l15;
            float ee = e2[c];
            #pragma unroll
            for (int t = 0; t < 4; ++t)
                #pragma unroll
                for (int r = 0; r < 4; ++r) {
                    float s = fmaf(-2.f, acc[t][nt][r], ee);
                    if (s < bestD[t][r]) { bestD[t][r] = s; bestI[t][r] = c; }
                }
        }
    }

    // reduce across the 16 lanes holding different codes for the same rows
    #pragma unroll
    for (int mask = 1; mask <= 8; mask <<= 1) {
        #pragma unroll
        for (int t = 0; t < 4; ++t)
            #pragma unroll
            for (int r = 0; r < 4; ++r) {
                float od = __shfl_xor(bestD[t][r], mask, 64);
                int   oi = __shfl_xor(bestI[t][r], mask, 64);
                if (od < bestD[t][r] || (od == bestD[t][r] && oi < bestI[t][r])) {
                    bestD[t][r] = od; bestI[t][r] = oi;
                }
            }
    }
    if (l15 == 0) {
        #pragma unroll
        for (int t = 0; t < 4; ++t)
            #pragma unroll
            for (int r = 0; r < 4; ++r) {
                int m = t * 16 + quad * 4 + r;   // C layout: row=(lane>>4)*4+reg
                wbD[wv * 64 + m] = bestD[t][r];
                wbI[wv * 64 + m] = bestI[t][r];
            }
    }
    __syncthreads();
    if (tid < 64) {
        float bd = wbD[tid]; int bi = wbI[tid];
        #pragma unroll
        for (int w = 1; w < 4; ++w) {
            float od = wbD[w * 64 + tid]; int oi = wbI[w * 64 + tid];
            if (od < bd || (od == bd && oi < bi)) { bd = od; bi = oi; }
        }
        out[IDX_OFF + n0 + tid] = (float)bi;
    }
}

// ---------------------------------------------------------------------------
// k_ema2: LDS-privatized segment sums + FUSED quantized-output/loss epilogue.
// v4: 1024 blocks (32 b x 16 dchunk x 2 HW-halves) -> 4 blocks/CU resident.
// Block stages its 8 emb rows (16KB) in LDS -> Q gather is an LDS lookup,
// Q written coalesced float4 alongside the z stream.
#define DC 8
__global__ __launch_bounds__(256) void k_ema2(const float* __restrict__ z,
                                              const float* __restrict__ emb,
                                              float* __restrict__ out,
                                              float* __restrict__ enc,
                                              float* __restrict__ esum,
                                              float* __restrict__ lossAcc) {
    __shared__ float acc[DC][K];   // 16 KB
    __shared__ float embs[DC][K];  // 16 KB
    __shared__ float cnt[K];       // 2 KB
    __shared__ float wred[4];

    const int tid = threadIdx.x;
    const int lane = tid & 63;
    const int wv = tid >> 6;
    const int half   = blockIdx.x & 1;
    const int dchunk = (blockIdx.x >> 1) & 15;
    const int b      = blockIdx.x >> 5;
    const int d0 = dchunk * DC;
    const bool doCnt = (dchunk == 0);

    for (int i = tid; i < DC * K; i += 256) {
        ((float*)acc)[i] = 0.f;
        ((float*)embs)[i] = emb[d0 * K + i];   // coalesced 16KB stage
    }
    if (doCnt) for (int i = tid; i < K; i += 256) cnt[i] = 0.f;
    __syncthreads();

    const float* zb  = z + b * ZSTRIDE_B;
    const float* idp = out + IDX_OFF + b * HW;
    float* qb = out + Q_OFF + b * ZSTRIDE_B;
    float lsum = 0.f;

    const int p0 = half * 2048;
    for (int t = p0; t < p0 + 2048; t += 1024) {
        const int p = t + 4 * tid;
        float4 iv = *(const float4*)(idp + p);
        int k0 = (int)iv.x;
        int k1 = (int)iv.y;
        int k2 = (int)iv.z;
        int k3 = (int)iv.w;
        if (doCnt) {
            atomicAdd(&cnt[k0], 1.f); atomicAdd(&cnt[k1], 1.f);
            atomicAdd(&cnt[k2], 1.f); atomicAdd(&cnt[k3], 1.f);
        }
        #pragma unroll
        for (int d = 0; d < DC; ++d) {
            float4 zv = *(const float4*)(zb + (d0 + d) * HW + p);
            atomicAdd(&acc[d][k0], zv.x);
            atomicAdd(&acc[d][k1], zv.y);
            atomicAdd(&acc[d][k2], zv.z);
            atomicAdd(&acc[d][k3], zv.w);
            float4 qv;
            qv.x = embs[d][k0]; qv.y = embs[d][k1];
            qv.z = embs[d][k2]; qv.w = embs[d][k3];
            *(float4*)(qb + (d0 + d) * HW + p) = qv;
            float dx = qv.x - zv.x; lsum = fmaf(dx, dx, lsum);
            float dy = qv.y - zv.y; lsum = fmaf(dy, dy, lsum);
            float dz2 = qv.z - zv.z; lsum = fmaf(dz2, dz2, lsum);
            float dw = qv.w - zv.w; lsum = fmaf(dw, dw, lsum);
        }
    }

    // loss partial: wave reduce -> LDS -> one atomic per block
    #pragma unroll
    for (int m = 32; m >= 1; m >>= 1) lsum += __shfl_xor(lsum, m, 64);
    if (lane == 0) wred[wv] = lsum;
    __syncthreads();   // also guarantees all LDS atomics complete before flush
    if (tid == 0) atomicAdd(lossAcc, wred[0] + wred[1] + wred[2] + wred[3]);

    for (int i = tid; i < DC * K; i += 256) {
        int d = i >> 9, k = i & 511;
        atomicAdd(&esum[(d0 + d) * K + k], acc[d][k]);
    }
    if (doCnt) for (int i = tid; i < K; i += 256) atomicAdd(&enc[i], cnt[i]);
}

// ---------------------------------------------------------------------------
// k_final: scalar part only (ncs, n, loss). 1 block.
__global__ __launch_bounds__(512) void k_final(const float* __restrict__ enc,
                                               const float* __restrict__ cs_in,
                                               const float* __restrict__ lossAcc,
                                               float* __restrict__ out,
                                               float* __restrict__ nnOut) {
    __shared__ float red[512];
    int k = threadIdx.x;
    float ncs = fmaf(cs_in[k], 0.99f, 0.01f * enc[k]);
    red[k] = ncs;
    out[NCS_OFF + k] = ncs;
    __syncthreads();
    for (int s = 256; s > 0; s >>= 1) {
        if (k < s) red[k] += red[k + s];
        __syncthreads();
    }
    if (k == 0) {
        nnOut[0] = fmaxf(red[0], 1e-5f);
        out[LOSS_OFF] = lossAcc[0] * 1.25f / 16777216.0f;
    }
}

// k_final2: embedding update, fully parallel (128 blocks = one per d), coalesced.
__global__ __launch_bounds__(512) void k_final2(const float* __restrict__ esum,
                                                const float* __restrict__ eavg_in,
                                                const float* __restrict__ nnIn,
                                                float* __restrict__ out) {
    int d = blockIdx.x;
    int k = threadIdx.x;
    float nn = nnIn[0];
    float ncs = out[NCS_OFF + k];
    float cs = (ncs + 1e-5f) / (nn + (float)K * 1e-5f) * nn;
    float ea = fmaf(eavg_in[d * K + k], 0.99f, 0.01f * esum[d * K + k]);
    out[NEA_OFF + d * K + k] = ea;
    out[NEMB_OFF + d * K + k] = ea / cs;
}

// ---------------------------------------------------------------------------
extern "C" void kernel_launch(void* const* d_in, const int* in_sizes, int n_in,
                              void* d_out, int out_size, void* d_ws, size_t ws_size,
                              hipStream_t stream) {
    const float* z     = (const float*)d_in[0];
    const float* emb   = (const float*)d_in[1];
    const float* cs_in = (const float*)d_in[2];
    const float* eavg  = (const float*)d_in[3];
    float* out = (float*)d_out;
    float* wsF = (float*)d_ws;

    // E2 (512) + ENC (512) are contiguous: one memset
    hipMemsetAsync(wsF + WS_E2, 0, 1024 * sizeof(float), stream);
    hipMemsetAsync(wsF + WS_LOSS, 0, sizeof(float), stream);

    k_prep<<<256, 256, 0, stream>>>(emb, (f16*)(wsF + WS_EHI), (f16*)(wsF + WS_ELO),
                                    wsF + WS_E2);
    k_assign<<<NPOS / 64, 256, 0, stream>>>(z,
                                            (const f16*)(wsF + WS_EHI),
                                            (const f16*)(wsF + WS_ELO),
                                            wsF + WS_E2, out);
    // e_hiP/e_loP no longer needed: reclaim region as esum
    hipMemsetAsync(wsF + WS_ESUM, 0, 65536 * sizeof(float), stream);
    k_ema2<<<1024, 256, 0, stream>>>(z, emb, out, wsF + WS_ENC, wsF + WS_ESUM,
                                     wsF + WS_LOSS);
    k_final<<<1, 512, 0, stream>>>(wsF + WS_ENC, cs_in, wsF + WS_LOSS,
                                   out, wsF + WS_NN);
    k_final2<<<128, 512, 0, stream>>>(wsF + WS_ESUM, eavg, wsF + WS_NN, out);
}

// Round 6
// 290.858 us; speedup vs baseline: 1.5695x; 1.0008x over previous
//
#include <hip/hip_runtime.h>
#include <hip/hip_bf16.h>
#include <float.h>

typedef _Float16 f16;
typedef __attribute__((ext_vector_type(8))) _Float16 half8;
typedef __attribute__((ext_vector_type(4))) float floatx4;

// Problem constants
#define DIM   128
#define HW    4096
#define NPOS  131072
#define K     512
#define ZSTRIDE_B 524288

// Output layout (floats)
#define Q_OFF     0
#define LOSS_OFF  16777216
#define IDX_OFF   16777217
#define NEMB_OFF  16908289
#define NCS_OFF   16973825
#define NEA_OFF   16974337

// Workspace layout (floats). e_hiP/e_loP OVERLAY the esum region: k_prep writes
// them, k_assign reads them, then esum is memset to 0 before k_ema2 uses it.
#define WS_E2    0
#define WS_ENC   512
#define WS_ESUM  1024
#define WS_EHI   1024          // f16[K*DIM] = 32768 floats
#define WS_ELO   33792         // f16[K*DIM] = 32768 floats (ends at 66560)
#define WS_LOSS  66560
#define WS_NN    66561

#define XST 136   // xs row stride (f16): 128 d + 8 pad -> 272B, 16B-aligned, 2-way banks

// ---------------------------------------------------------------------------
// k_prep: split codebook into f16 hi/lo in a FRAGMENT-LINEAR packed layout:
//   g = c>>4, r = c&15, dc = dd>>5, quad = (dd>>3)&3, j = dd&7
//   packed[(g*4+dc)*512 + quad*128 + r*8 + j]
// B-fragment load for a 16x16 code tile/k-chunk = 64 lanes x 16B CONTIGUOUS.
// Fused e2 via NATIVE fp atomics (unsafeAtomicAdd -> global_atomic_add_f32).
// Plain atomicAdd(float*) compiles to a CAS loop (safe-FP default) and
// serialized ~30us at 128-way contention here.
__global__ __launch_bounds__(256) void k_prep(const float* __restrict__ emb,
                                              f16* __restrict__ ehiP,
                                              f16* __restrict__ eloP,
                                              float* __restrict__ e2) {
    int lin = blockIdx.x * 256 + threadIdx.x;   // 65536 threads
    int d = lin >> 9, k = lin & 511;
    float v = emb[lin];                          // coalesced read
    unsafeAtomicAdd(&e2[k], v * v);              // native fp32 atomic
    f16 h = (f16)v;
    f16 l = (f16)(v - (float)h);
    int g = k >> 4, r = k & 15;
    int dc = d >> 5, w = d & 31, quad = w >> 3, j = w & 7;
    int idx = (g * 4 + dc) * 512 + quad * 128 + r * 8 + j;
    ehiP[idx] = h;                               // scattered 2B writes (one-shot, tiny)
    eloP[idx] = l;
}

// ---------------------------------------------------------------------------
// k_assign (MFMA): 64 positions/block, all 512 codes, D=128.
// score = e2[c] - 2*dot(x,e); dot via 3-pass f16-split MFMA (hh + lh + hl).
// 4 code-chunks of 128 (acc[4][2] = 32 VGPR), (256,2) pin -> 4 waves/SIMD.
// Stage loop split load-all/convert-all so 32 global loads issue in one burst.
__global__ __launch_bounds__(256, 2) void k_assign(const float* __restrict__ z,
                                                   const f16* __restrict__ ehiP,
                                                   const f16* __restrict__ eloP,
                                                   const float* __restrict__ e2,
                                                   float* __restrict__ out) {
    __shared__ f16 xs_h[64 * XST];
    __shared__ f16 xs_l[64 * XST];
    __shared__ float wbD[256];
    __shared__ int   wbI[256];

    const int tid  = threadIdx.x;
    const int lane = tid & 63;
    const int wv   = tid >> 6;
    const int n0   = blockIdx.x * 64;
    const int b    = n0 >> 12;
    const int hw0  = n0 & 4095;
    const float* zb = z + b * ZSTRIDE_B + hw0;
    const int l15  = lane & 15;
    const int quad = lane >> 4;

    // ---- stage X split (64 pos x 128 d): phase 1 = issue all 32 loads,
    // phase 2 = convert + packed u32 LDS writes. Static indexing throughout.
    float sv0[16], sv1[16];
    #pragma unroll
    for (int it = 0; it < 16; ++it) {
        int lin = tid + it * 256;
        int i  = lin & 63;          // position (lanes consecutive -> coalesced)
        int dp = lin >> 6;          // d-pair 0..63
        sv0[it] = zb[(2 * dp) * HW + i];
        sv1[it] = zb[(2 * dp + 1) * HW + i];
    }
    #pragma unroll
    for (int it = 0; it < 16; ++it) {
        int lin = tid + it * 256;
        int i  = lin & 63;
        int dp = lin >> 6;
        float v0 = sv0[it], v1 = sv1[it];
        f16 h0 = (f16)v0; f16 l0 = (f16)(v0 - (float)h0);
        f16 h1 = (f16)v1; f16 l1 = (f16)(v1 - (float)h1);
        union { f16 h[2]; unsigned int u; } ph, pl;
        ph.h[0] = h0; ph.h[1] = h1;
        pl.h[0] = l0; pl.h[1] = l1;
        *(unsigned int*)&xs_h[i * XST + 2 * dp] = ph.u;
        *(unsigned int*)&xs_l[i * XST + 2 * dp] = pl.u;
    }
    __syncthreads();

    float bestD[4][4];
    int   bestI[4][4];
    #pragma unroll
    for (int t = 0; t < 4; ++t)
        #pragma unroll
        for (int r = 0; r < 4; ++r) { bestD[t][r] = FLT_MAX; bestI[t][r] = 0x7fffffff; }

    const half8* gh = (const half8*)ehiP;
    const half8* gl = (const half8*)eloP;

    for (int cc = 0; cc < 4; ++cc) {       // 4 chunks x 128 codes
        floatx4 acc[4][2];
        #pragma unroll
        for (int t = 0; t < 4; ++t)
            #pragma unroll
            for (int nt = 0; nt < 2; ++nt) acc[t][nt] = (floatx4){0.f, 0.f, 0.f, 0.f};

        for (int dc = 0; dc < 4; ++dc) {
            // A fragments: A[m = t*16 + (lane&15)][k = quad*8 + j]
            half8 ah[4], al[4];
            #pragma unroll
            for (int t = 0; t < 4; ++t) {
                int off = (t * 16 + l15) * XST + dc * 32 + quad * 8;
                ah[t] = *(const half8*)&xs_h[off];
                al[t] = *(const half8*)&xs_l[off];
            }
            #pragma unroll
            for (int nt = 0; nt < 2; ++nt) {
                // B fragment: wave-contiguous 1KB load from packed codebook
                int g  = cc * 8 + wv * 2 + nt;      // 16-code group
                int bi = (g * 4 + dc) * 64 + lane;
                half8 bh = gh[bi];
                half8 bl = gl[bi];
                #pragma unroll
                for (int t = 0; t < 4; ++t) {
                    acc[t][nt] = __builtin_amdgcn_mfma_f32_16x16x32_f16(ah[t], bh, acc[t][nt], 0, 0, 0);
                    acc[t][nt] = __builtin_amdgcn_mfma_f32_16x16x32_f16(al[t], bh, acc[t][nt], 0, 0, 0);
                    acc[t][nt] = __builtin_amdgcn_mfma_f32_16x16x32_f16(ah[t], bl, acc[t][nt], 0, 0, 0);
                }
            }
        }
        // fold scores into best (codes ascend across cc,nt for fixed lane -> strict <)
        #pragma unroll
        for (int nt = 0; nt < 2; ++nt) {
            int c = cc * 128 + wv * 32 + nt * 16 + l15;
            float ee = e2[c];
            #pragma unroll
            for (int t = 0; t < 4; ++t)
                #pragma unroll
                for (int r = 0; r < 4; ++r) {
                    float s = fmaf(-2.f, acc[t][nt][r], ee);
                    if (s < bestD[t][r]) { bestD[t][r] = s; bestI[t][r] = c; }
                }
        }
    }

    // reduce across the 16 lanes holding different codes for the same rows
    #pragma unroll
    for (int mask = 1; mask <= 8; mask <<= 1) {
        #pragma unroll
        for (int t = 0; t < 4; ++t)
            #pragma unroll
            for (int r = 0; r < 4; ++r) {
                float od = __shfl_xor(bestD[t][r], mask, 64);
                int   oi = __shfl_xor(bestI[t][r], mask, 64);
                if (od < bestD[t][r] || (od == bestD[t][r] && oi < bestI[t][r])) {
                    bestD[t][r] = od; bestI[t][r] = oi;
                }
            }
    }
    if (l15 == 0) {
        #pragma unroll
        for (int t = 0; t < 4; ++t)
            #pragma unroll
            for (int r = 0; r < 4; ++r) {
                int m = t * 16 + quad * 4 + r;   // C layout: row=(lane>>4)*4+reg
                wbD[wv * 64 + m] = bestD[t][r];
                wbI[wv * 64 + m] = bestI[t][r];
            }
    }
    __syncthreads();
    if (tid < 64) {
        float bd = wbD[tid]; int bi = wbI[tid];
        #pragma unroll
        for (int w = 1; w < 4; ++w) {
            float od = wbD[w * 64 + tid]; int oi = wbI[w * 64 + tid];
            if (od < bd || (od == bd && oi < bi)) { bd = od; bi = oi; }
        }
        out[IDX_OFF + n0 + tid] = (float)bi;
    }
}

// ---------------------------------------------------------------------------
// k_ema2: LDS-privatized segment sums + FUSED quantized-output/loss epilogue.
// v6: 2048 blocks (32 b x 16 dchunk x 4 HW-quarters) -> 4 blocks/CU, 2 passes.
// All global fp accumulations use unsafeAtomicAdd (native global_atomic_add_f32)
// -- the plain atomicAdd CAS-loop on the single lossAcc address serialized
// ~60us across blocks (the r3->r5 fixed-tail arithmetic: 150=60+90, 105=60+45).
#define DC 8
__global__ __launch_bounds__(256) void k_ema2(const float* __restrict__ z,
                                              const float* __restrict__ emb,
                                              float* __restrict__ out,
                                              float* __restrict__ enc,
                                              float* __restrict__ esum,
                                              float* __restrict__ lossAcc) {
    __shared__ float acc[DC][K];   // 16 KB
    __shared__ float embs[DC][K];  // 16 KB
    __shared__ float cnt[K];       // 2 KB
    __shared__ float wred[4];

    const int tid = threadIdx.x;
    const int lane = tid & 63;
    const int wv = tid >> 6;
    const int quarter = blockIdx.x & 3;
    const int dchunk  = (blockIdx.x >> 2) & 15;
    const int b       = blockIdx.x >> 6;
    const int d0 = dchunk * DC;
    const bool doCnt = (dchunk == 0);

    for (int i = tid; i < DC * K; i += 256) {
        ((float*)acc)[i] = 0.f;
        ((float*)embs)[i] = emb[d0 * K + i];   // coalesced 16KB stage
    }
    if (doCnt) for (int i = tid; i < K; i += 256) cnt[i] = 0.f;
    __syncthreads();

    const float* zb  = z + b * ZSTRIDE_B;
    const float* idp = out + IDX_OFF + b * HW;
    float* qb = out + Q_OFF + b * ZSTRIDE_B;
    float lsum = 0.f;

    {
        const int p = quarter * 1024 + 4 * tid;
        float4 iv = *(const float4*)(idp + p);
        int k0 = (int)iv.x;
        int k1 = (int)iv.y;
        int k2 = (int)iv.z;
        int k3 = (int)iv.w;
        if (doCnt) {
            atomicAdd(&cnt[k0], 1.f); atomicAdd(&cnt[k1], 1.f);
            atomicAdd(&cnt[k2], 1.f); atomicAdd(&cnt[k3], 1.f);
        }
        #pragma unroll
        for (int d = 0; d < DC; ++d) {
            float4 zv = *(const float4*)(zb + (d0 + d) * HW + p);
            atomicAdd(&acc[d][k0], zv.x);
            atomicAdd(&acc[d][k1], zv.y);
            atomicAdd(&acc[d][k2], zv.z);
            atomicAdd(&acc[d][k3], zv.w);
            float4 qv;
            qv.x = embs[d][k0]; qv.y = embs[d][k1];
            qv.z = embs[d][k2]; qv.w = embs[d][k3];
            *(float4*)(qb + (d0 + d) * HW + p) = qv;
            float dx = qv.x - zv.x; lsum = fmaf(dx, dx, lsum);
            float dy = qv.y - zv.y; lsum = fmaf(dy, dy, lsum);
            float dz2 = qv.z - zv.z; lsum = fmaf(dz2, dz2, lsum);
            float dw = qv.w - zv.w; lsum = fmaf(dw, dw, lsum);
        }
    }

    // loss partial: wave reduce -> LDS -> ONE native atomic per block
    #pragma unroll
    for (int m = 32; m >= 1; m >>= 1) lsum += __shfl_xor(lsum, m, 64);
    if (lane == 0) wred[wv] = lsum;
    __syncthreads();   // also guarantees all LDS atomics complete before flush
    if (tid == 0) unsafeAtomicAdd(lossAcc, wred[0] + wred[1] + wred[2] + wred[3]);

    for (int i = tid; i < DC * K; i += 256) {
        int d = i >> 9, k = i & 511;
        unsafeAtomicAdd(&esum[(d0 + d) * K + k], acc[d][k]);
    }
    if (doCnt) for (int i = tid; i < K; i += 256) unsafeAtomicAdd(&enc[i], cnt[i]);
}

// ---------------------------------------------------------------------------
// k_final: scalar part only (ncs, n, loss). 1 block.
__global__ __launch_bounds__(512) void k_final(const float* __restrict__ enc,
                                               const float* __restrict__ cs_in,
                                               const float* __restrict__ lossAcc,
                                               float* __restrict__ out,
                                               float* __restrict__ nnOut) {
    __shared__ float red[512];
    int k = threadIdx.x;
    float ncs = fmaf(cs_in[k], 0.99f, 0.01f * enc[k]);
    red[k] = ncs;
    out[NCS_OFF + k] = ncs;
    __syncthreads();
    for (int s = 256; s > 0; s >>= 1) {
        if (k < s) red[k] += red[k + s];
        __syncthreads();
    }
    if (k == 0) {
        nnOut[0] = fmaxf(red[0], 1e-5f);
        out[LOSS_OFF] = lossAcc[0] * 1.25f / 16777216.0f;
    }
}

// k_final2: embedding update, fully parallel (128 blocks = one per d), coalesced.
__global__ __launch_bounds__(512) void k_final2(const float* __restrict__ esum,
                                                const float* __restrict__ eavg_in,
                                                const float* __restrict__ nnIn,
                                                float* __restrict__ out) {
    int d = blockIdx.x;
    int k = threadIdx.x;
    float nn = nnIn[0];
    float ncs = out[NCS_OFF + k];
    float cs = (ncs + 1e-5f) / (nn + (float)K * 1e-5f) * nn;
    float ea = fmaf(eavg_in[d * K + k], 0.99f, 0.01f * esum[d * K + k]);
    out[NEA_OFF + d * K + k] = ea;
    out[NEMB_OFF + d * K + k] = ea / cs;
}

// ---------------------------------------------------------------------------
extern "C" void kernel_launch(void* const* d_in, const int* in_sizes, int n_in,
                              void* d_out, int out_size, void* d_ws, size_t ws_size,
                              hipStream_t stream) {
    const float* z     = (const float*)d_in[0];
    const float* emb   = (const float*)d_in[1];
    const float* cs_in = (const float*)d_in[2];
    const float* eavg  = (const float*)d_in[3];
    float* out = (float*)d_out;
    float* wsF = (float*)d_ws;

    // E2 (512) + ENC (512) are contiguous: one memset
    hipMemsetAsync(wsF + WS_E2, 0, 1024 * sizeof(float), stream);
    hipMemsetAsync(wsF + WS_LOSS, 0, sizeof(float), stream);

    k_prep<<<256, 256, 0, stream>>>(emb, (f16*)(wsF + WS_EHI), (f16*)(wsF + WS_ELO),
                                    wsF + WS_E2);
    k_assign<<<NPOS / 64, 256, 0, stream>>>(z,
                                            (const f16*)(wsF + WS_EHI),
                                            (const f16*)(wsF + WS_ELO),
                                            wsF + WS_E2, out);
    // e_hiP/e_loP no longer needed: reclaim region as esum
    hipMemsetAsync(wsF + WS_ESUM, 0, 65536 * sizeof(float), stream);
    k_ema2<<<2048, 256, 0, stream>>>(z, emb, out, wsF + WS_ENC, wsF + WS_ESUM,
                                     wsF + WS_LOSS);
    k_final<<<1, 512, 0, stream>>>(wsF + WS_ENC, cs_in, wsF + WS_LOSS,
                                   out, wsF + WS_NN);
    k_final2<<<128, 512, 0, stream>>>(wsF + WS_ESUM, eavg, wsF + WS_NN, out);
}